// Round 1
// baseline (331.707 us; speedup 1.0000x reference)
//
#include <hip/hip_runtime.h>

#define D16 16
#define KC 512
// tokens: B(8) * heads(8) * HW(4096)
#define NTOK (8 * 8 * 4096)

// workspace layout:
//   [0, 512*17*4)            : M   = K x 17 fp32  (O_tV sums | count)
//   [36864, 36864 + NTOK*2)  : idx = ushort per token

__device__ __forceinline__ unsigned pack2bf(float a, float b) {
    unsigned ua = __float_as_uint(a), ub = __float_as_uint(b);
    ua = (ua + 0x7fffu + ((ua >> 16) & 1u)) >> 16;          // RNE to bf16, low half
    ub = (ub + 0x7fffu + ((ub >> 16) & 1u)) & 0xffff0000u;  // RNE to bf16, high half
    return ua | ub;
}

// ---------------- kernel 1: nearest-code assignment ----------------
extern "C" __global__ __launch_bounds__(256)
void vq_assign(const float* __restrict__ qkv, const float* __restrict__ cb,
               unsigned short* __restrict__ idx)
{
    __shared__ float s_cb[KC * D16];   // 32 KB
    __shared__ float s_cn[KC];         // 2 KB
    for (int i = threadIdx.x; i < KC * D16; i += 256) s_cb[i] = cb[i];
    __syncthreads();
    for (int j = threadIdx.x; j < KC; j += 256) {
        float s = 0.f;
#pragma unroll
        for (int d = 0; d < D16; ++d) { float c = s_cb[j * D16 + d]; s = fmaf(c, c, s); }
        s_cn[j] = s;
    }
    __syncthreads();

    // two tokens per thread: n0 and n0+256, block covers 512 consecutive tokens
    int n0 = blockIdx.x * 512 + threadIdx.x;
    int n1 = n0 + 256;

    int bh0 = n0 >> 12, hw0 = n0 & 4095;
    int bh1 = n1 >> 12, hw1 = n1 & 4095;
    const float* b0 = qkv + (size_t)bh0 * (48 * 4096) + hw0;
    const float* b1 = qkv + (size_t)bh1 * (48 * 4096) + hw1;

    float k0[D16], k1[D16];
#pragma unroll
    for (int d = 0; d < D16; ++d) k0[d] = b0[(16 + d) * 4096];
#pragma unroll
    for (int d = 0; d < D16; ++d) k1[d] = b1[(16 + d) * 4096];

    float best0 = 3.4e38f, best1 = 3.4e38f;
    int bj0 = 0, bj1 = 0;
#pragma unroll 2
    for (int j = 0; j < KC; ++j) {
        const float4* cr = reinterpret_cast<const float4*>(s_cb + j * D16);
        float4 x0 = cr[0], x1 = cr[1], x2 = cr[2], x3 = cr[3];
        float c[D16] = {x0.x, x0.y, x0.z, x0.w, x1.x, x1.y, x1.z, x1.w,
                        x2.x, x2.y, x2.z, x2.w, x3.x, x3.y, x3.z, x3.w};
        float dot0 = 0.f, dot1 = 0.f;
#pragma unroll
        for (int d = 0; d < D16; ++d) {
            dot0 = fmaf(k0[d], c[d], dot0);
            dot1 = fmaf(k1[d], c[d], dot1);
        }
        float cn = s_cn[j];
        float dist0 = fmaf(-2.f, dot0, cn);
        float dist1 = fmaf(-2.f, dot1, cn);
        if (dist0 < best0) { best0 = dist0; bj0 = j; }
        if (dist1 < best1) { best1 = dist1; bj1 = j; }
    }
    idx[n0] = (unsigned short)bj0;
    idx[n1] = (unsigned short)bj1;
}

// ---------------- kernel 2: segment sum of v + counts ----------------
extern "C" __global__ __launch_bounds__(256)
void vq_segsum(const float* __restrict__ qkv, const unsigned short* __restrict__ idx,
               float* __restrict__ M)
{
    __shared__ float s_acc[KC * 17];   // 34.8 KB
    for (int i = threadIdx.x; i < KC * 17; i += 256) s_acc[i] = 0.f;
    __syncthreads();

    for (int n = blockIdx.x * 256 + threadIdx.x; n < NTOK; n += gridDim.x * 256) {
        int bh = n >> 12, hw = n & 4095;
        const float* bv = qkv + (size_t)bh * (48 * 4096) + hw + 32 * 4096;
        int bj = idx[n];
#pragma unroll
        for (int d = 0; d < D16; ++d)
            atomicAdd(&s_acc[bj * 17 + d], bv[d * 4096]);
        atomicAdd(&s_acc[bj * 17 + 16], 1.0f);
    }
    __syncthreads();
    for (int i = threadIdx.x; i < KC * 17; i += 256)
        atomicAdd(&M[i], s_acc[i]);
}

// ---------------- kernel 3: softmax-weighted gather ----------------
extern "C" __global__ __launch_bounds__(256)
void vq_attend(const float* __restrict__ qkv, const float* __restrict__ cb,
               const float* __restrict__ M, float* __restrict__ out)
{
    __shared__ float s_cb[KC * D16];    // 32 KB fp32 codebook
    __shared__ float s_cnt[KC];         // 2 KB fp32 counts
    __shared__ unsigned s_mv[KC * 8];   // 16 KB bf16x2-packed O_tV

    for (int i = threadIdx.x; i < KC * D16; i += 256) s_cb[i] = cb[i];
    for (int j = threadIdx.x; j < KC; j += 256) s_cnt[j] = M[j * 17 + 16];
    for (int i = threadIdx.x; i < KC * 8; i += 256) {
        int j = i >> 3, p = i & 7;
        s_mv[i] = pack2bf(M[j * 17 + 2 * p], M[j * 17 + 2 * p + 1]);
    }
    __syncthreads();

    int n0 = blockIdx.x * 512 + threadIdx.x;
    int n1 = n0 + 256;
    int bh0 = n0 >> 12, hw0 = n0 & 4095;
    int bh1 = n1 >> 12, hw1 = n1 & 4095;
    const float* b0 = qkv + (size_t)bh0 * (48 * 4096) + hw0;
    const float* b1 = qkv + (size_t)bh1 * (48 * 4096) + hw1;

    float q0[D16], q1[D16];
#pragma unroll
    for (int d = 0; d < D16; ++d) q0[d] = b0[d * 4096];
#pragma unroll
    for (int d = 0; d < D16; ++d) q1[d] = b1[d * 4096];

    float acc0[17], acc1[17];
#pragma unroll
    for (int d = 0; d < 17; ++d) { acc0[d] = 0.f; acc1[d] = 0.f; }

    for (int j = 0; j < KC; ++j) {
        const float4* cr = reinterpret_cast<const float4*>(s_cb + j * D16);
        float4 x0 = cr[0], x1 = cr[1], x2 = cr[2], x3 = cr[3];
        float c[D16] = {x0.x, x0.y, x0.z, x0.w, x1.x, x1.y, x1.z, x1.w,
                        x2.x, x2.y, x2.z, x2.w, x3.x, x3.y, x3.z, x3.w};
        float dot0 = 0.f, dot1 = 0.f;
#pragma unroll
        for (int d = 0; d < D16; ++d) {
            dot0 = fmaf(q0[d], c[d], dot0);
            dot1 = fmaf(q1[d], c[d], dot1);
        }
        float w0 = __expf(dot0);
        float w1 = __expf(dot1);

        const uint4* mr = reinterpret_cast<const uint4*>(s_mv + j * 8);
        uint4 ma = mr[0], mb = mr[1];
        unsigned mu[8] = {ma.x, ma.y, ma.z, ma.w, mb.x, mb.y, mb.z, mb.w};
        float mv[D16];
#pragma unroll
        for (int p = 0; p < 8; ++p) {
            mv[2 * p]     = __uint_as_float(mu[p] << 16);
            mv[2 * p + 1] = __uint_as_float(mu[p] & 0xffff0000u);
        }
#pragma unroll
        for (int d = 0; d < D16; ++d) {
            acc0[d] = fmaf(w0, mv[d], acc0[d]);
            acc1[d] = fmaf(w1, mv[d], acc1[d]);
        }
        float cnt = s_cnt[j];
        acc0[16] = fmaf(w0, cnt, acc0[16]);
        acc1[16] = fmaf(w1, cnt, acc1[16]);
    }

    float inv0 = 1.0f / (acc0[16] + 1e-15f);
    float inv1 = 1.0f / (acc1[16] + 1e-15f);
    float* o0 = out + (size_t)n0 * D16;
    float* o1 = out + (size_t)n1 * D16;
#pragma unroll
    for (int d = 0; d < D16; ++d) o0[d] = acc0[d] * inv0;
#pragma unroll
    for (int d = 0; d < D16; ++d) o1[d] = acc1[d] * inv1;
}

extern "C" void kernel_launch(void* const* d_in, const int* in_sizes, int n_in,
                              void* d_out, int out_size, void* d_ws, size_t ws_size,
                              hipStream_t stream) {
    const float* qkv = (const float*)d_in[0];   // (8, 384, 64, 64) fp32
    const float* cb  = (const float*)d_in[1];   // (512, 16) fp32
    float* out = (float*)d_out;                 // (8, 128, 64, 64) fp32

    float* M = (float*)d_ws;                                   // K x 17 fp32
    unsigned short* idx = (unsigned short*)((char*)d_ws + 36864);

    hipMemsetAsync(d_ws, 0, KC * 17 * sizeof(float), stream);

    vq_assign<<<NTOK / 512, 256, 0, stream>>>(qkv, cb, idx);
    vq_segsum<<<256, 256, 0, stream>>>(qkv, idx, M);
    vq_attend<<<NTOK / 512, 256, 0, stream>>>(qkv, cb, M, out);
}